// Round 19
// baseline (160.046 us; speedup 1.0000x reference)
//
#include <hip/hip_runtime.h>
#include <hip/hip_fp16.h>
#include <math.h>

#define TT 2048
#define CC 64
#define BB 32
#define PADL 512
#define ROWW 2112          // 1024 outputs + 2*512 halo + 64 slack (MFMA K-padding reads to 2063)

typedef __attribute__((ext_vector_type(8))) short short8;
typedef __attribute__((ext_vector_type(4))) float float4v;
typedef _Float16 half8 __attribute__((ext_vector_type(8)));

// Toeplitz A-fragment table: 67 K-steps x 64 lanes x 8 bf16 (hi only)
#define NSTEPS 67
__device__ unsigned short g_afrag_hi[NSTEPS * 64 * 8];

__device__ __forceinline__ float fast_rcp(float x) { return __builtin_amdgcn_rcpf(x); }
__device__ __forceinline__ float fast_exp2(float x) { return __builtin_amdgcn_exp2f(x); }
__device__ __forceinline__ float fast_log2(float x) { return __builtin_amdgcn_logf(x); }

__device__ __forceinline__ unsigned short f2bf(float x) {  // RNE bf16 round
  union { float f; unsigned u; } v; v.f = x;
  unsigned r = (v.u + 0x7FFFu + ((v.u >> 16) & 1u)) >> 16;
  return (unsigned short)r;
}
__device__ __forceinline__ unsigned h2u(__half2 h) { union { __half2 h; unsigned u; } c; c.h = h; return c.u; }

// packed-f16 GELU: x*sigma(1.595769x+0.0713548x^3); exp(-s)=exp2(x*(-2.3020231-0.10294217x^2))
__device__ __forceinline__ __half2 gelu_h2(__half2 x) {
  const __half2 c1 = __float2half2_rn(-0.10294217f);
  const __half2 c0 = __float2half2_rn(-2.3020231f);
  const __half2 one = __float2half2_rn(1.0f);
  __half2 u = __hmul2(x, x);
  __half2 w = __hmul2(x, __hfma2(c1, u, c0));
  __half2 e = h2exp2(w);
  return __hmul2(x, h2rcp(__hadd2(e, one)));
}

__device__ __forceinline__ void init_frag_body(int bid, int nb, int tid,
                                               float* ktap, double* ssum) {
  const int   Rr[5]  = {32, 64, 128, 256, 512};
  const float sg[5]  = {8.f, 16.f, 32.f, 64.f, 128.f};
  const int   off[5] = {0, 72, 208, 472, 984};

  for (int idx = tid; idx < 2016; idx += 256) {
    int s = (idx < 72) ? 0 : (idx < 208) ? 1 : (idx < 472) ? 2 : (idx < 984) ? 3 : 4;
    int d = idx - off[s];
    float v = 0.f;
    if (d <= 2 * Rr[s]) {
      float n = (float)(d - Rr[s]) / sg[s];
      v = __expf(-0.5f * n * n);
    }
    ktap[idx] = v;
  }
  __syncthreads();
  if (tid < 5) {
    double sum = 0.0;
    for (int d = 0; d <= 2 * Rr[tid]; ++d) sum += (double)ktap[off[tid] + d];
    ssum[tid] = 1.0 / (sum + 1e-12);
  }
  __syncthreads();
  for (int idx = tid; idx < 2016; idx += 256) {
    int s = (idx < 72) ? 0 : (idx < 208) ? 1 : (idx < 472) ? 2 : (idx < 984) ? 3 : 4;
    ktap[idx] *= (float)ssum[s];
  }
  __syncthreads();

  const int cum[5] = {0, 3, 8, 17, 34};
  for (int e = bid * 256 + tid; e < NSTEPS * 64; e += nb * 256) {
    int stg = e >> 6, lane = e & 63;
    int s = (stg < 3) ? 0 : (stg < 8) ? 1 : (stg < 17) ? 2 : (stg < 34) ? 3 : 4;
    int st = stg - cum[s];
    int i = lane & 15, h = lane >> 4;
    for (int e2 = 0; e2 < 8; ++e2) {
      int d = st * 32 + 8 * h + e2 - i;
      float v = (d >= 0 && d <= 2 * Rr[s]) ? ktap[off[s] + d] : 0.f;
      g_afrag_hi[e * 8 + e2] = f2bf(v);
    }
  }
}

__global__ void init_frag() {
  __shared__ float ktap[2016];
  __shared__ double ssum[5];
  init_frag_body(blockIdx.x, gridDim.x, threadIdx.x, ktap, ssum);
}

// ---- transpose x [B,T,C] fp32 -> xT [B,C,T] bf16; blocks 0..7 also init frags ----
__global__ void transpose_in(const float* __restrict__ x, unsigned short* __restrict__ xT) {
  __shared__ float tile[64][65];
  __shared__ float ktap[2016];
  __shared__ double ssum[5];
  const int tid = threadIdx.x;
  const int b = blockIdx.x >> 5;
  const int t0 = (blockIdx.x & 31) * 64;

  const float* src = x + ((size_t)b * TT + t0) * CC;
  #pragma unroll
  for (int k = 0; k < 16; ++k) {
    int idx = k * 256 + tid;
    int row = idx >> 6, col = idx & 63;
    tile[row][col] = src[(size_t)row * CC + col];
  }
  __syncthreads();
  unsigned short* dst = xT + (size_t)b * CC * TT + t0;
  #pragma unroll
  for (int k = 0; k < 16; ++k) {
    int idx = k * 256 + tid;
    int c = idx >> 6, tt = idx & 63;
    dst[(size_t)c * TT + tt] = f2bf(tile[tt][c]);
  }
  if (blockIdx.x < 8) init_frag_body(blockIdx.x, 8, tid, ktap, ssum);
}

// ---- transpose outT [B,C,T] fp32 -> out [B,T,C] fp32 ----
__global__ void transpose_out(const float* __restrict__ outT, float* __restrict__ out) {
  __shared__ float tile[64][65];
  const int tid = threadIdx.x;
  const int b = blockIdx.x >> 5;
  const int t0 = (blockIdx.x & 31) * 64;

  const float* src = outT + (size_t)b * CC * TT + t0;
  #pragma unroll
  for (int k = 0; k < 16; ++k) {
    int idx = k * 256 + tid;
    int cc2 = idx >> 6, tt = idx & 63;
    tile[cc2][tt] = src[(size_t)cc2 * TT + tt];
  }
  __syncthreads();
  float* dst = out + ((size_t)b * TT + t0) * CC;
  #pragma unroll
  for (int k = 0; k < 16; ++k) {
    int idx = k * 256 + tid;
    int tt = idx >> 6, cc2 = idx & 63;
    dst[(size_t)tt * CC + cc2] = tile[cc2][tt];
  }
}

template <int WSPATH>
__launch_bounds__(256, 8)
__global__ void fused_main_t(const float* __restrict__ x, const unsigned short* __restrict__ xT,
                             const float* __restrict__ W1, const float* __restrict__ b1,
                             const float* __restrict__ W2, const float* __restrict__ b2,
                             const float* __restrict__ W3, const float* __restrict__ b3,
                             float* __restrict__ outT, float* __restrict__ out) {
  __shared__ unsigned short row_hi[ROWW];
  __shared__ __half gbuf[4][5][16][16];   // gates; s=0..2 aliased as feats; XOR-swizzled cols

  const int tid = threadIdx.x;
  const int blk = blockIdx.x;
  const int c = blk & (CC - 1);
  const int tblk = (blk >> 6) & 1;
  const int b = blk >> 7;
  const int tbase = tblk * 1024;

  // ---- stage reflect-padded window as bf16 ----
  if (WSPATH) {
    const unsigned short* xtr = xT + (size_t)(b * CC + c) * TT;
    for (int i2 = tid; i2 < ROWW; i2 += 256) {
      int t = tbase + i2 - PADL;
      t = (t < 0) ? -t : t;
      t = (t >= TT) ? (2 * TT - 2 - t) : t;
      row_hi[i2] = xtr[t];
    }
  } else {
    const float* xrow = x + (size_t)b * TT * CC + c;
    for (int i2 = tid; i2 < ROWW; i2 += 256) {
      int t = tbase + i2 - PADL;
      t = (t < 0) ? -t : t;
      t = (t >= TT) ? (2 * TT - 2 - t) : t;
      row_hi[i2] = f2bf(xrow[(size_t)t * CC]);
    }
  }
  __syncthreads();

  const int lane = tid & 63;
  const int wvi = tid >> 6;

  // ======== Phase A1: sliding-window stats (bf16 x), 4 elements/thread ========
  {
    const int kk = tid >> 1;
    const int sh = (tid & 1) * 4;
    const int t0 = tid * 4;

    float w24[24];
    {
      const unsigned short* ph = &row_hi[PADL + 8 * kk - 8];
      unsigned hw[12];
      *(uint4*)&hw[0] = *(const uint4*)ph;
      *(uint4*)&hw[4] = *(const uint4*)(ph + 8);
      *(uint4*)&hw[8] = *(const uint4*)(ph + 16);
      #pragma unroll
      for (int m2 = 0; m2 < 12; ++m2) {
        union { unsigned u; float f; } a, bb;
        a.u  = (hw[m2] & 0xFFFFu) << 16;
        bb.u = hw[m2] & 0xFFFF0000u;
        w24[2 * m2]     = a.f;
        w24[2 * m2 + 1] = bb.f;
      }
    }

    float sm = 0.f, sq = 0.f, scv = 0.f;
    #pragma unroll
    for (int j = 0; j < 16; ++j) {
      float v = w24[sh + 1 + j];
      sm += v;
      sq  = fmaf(v, v, sq);
      scv = fmaf(v, (float)j - 7.5f, scv);
    }

    #pragma unroll
    for (int i = 0; i < 4; ++i) {
      const float xv   = w24[sh + i + 8];
      const float mean = sm * 0.0625f;
      const float ex2  = sq * 0.0625f;
      const float var  = fmaxf(ex2 - mean * mean, 0.f);
      const float slope = scv * (1.0f / 340.0f);
      const float stdv = sqrtf(var + 1e-6f);
      float z = (xv - mean) * fast_rcp(stdv);
      z = fminf(fmaxf(z, -10.f), 10.f);
      float lv = fast_log2(var + 1e-6f) * 0.069314718f;   // *ln2/10 = ln(.)/10
      float ns = slope * fast_rcp(stdv + 1e-6f);
      ns = fminf(fmaxf(ns, -10.f), 10.f);

      const int e = t0 + i;
      const int ch = e >> 8, rr = e & 15, pp = (e >> 4) & 15;
      const int ppx = pp ^ ((rr >> 2) << 2);
      gbuf[ch][0][rr][ppx] = __float2half(z);
      gbuf[ch][1][rr][ppx] = __float2half(lv);
      gbuf[ch][2][rr][ppx] = __float2half(ns);

      if (i < 3) {
        const float xo = w24[sh + i + 1], xn = w24[sh + i + 17];
        scv = fmaf(8.5f, xo, fmaf(7.5f, xn, scv - sm));
        sm += (xn - xo);
        sq = fmaf(xn, xn, sq);
        sq = fmaf(-xo, xo, sq);
      }
    }
  }

  // ======== Phase A2: MLP, all three layers on/around MFMA (chunk = wvi) ======
  {
    const int kg = lane >> 4;        // quarter index q
    const int m  = lane & 15;        // element column
    const int ch = wvi;
    const int mx = (m >> 2) << 2;    // XOR swizzle term for row m

    // W2 A-fragments (single-pass f16)
    half8 w2f0, w2f1;
    {
      const float* p0 = W2 + (size_t)m * 32 + 8 * kg;
      const float* p1 = W2 + (size_t)(16 + m) * 32 + 8 * kg;
      #pragma unroll
      for (int e2 = 0; e2 < 8; ++e2) {
        w2f0[e2] = (_Float16)p0[e2];
        w2f1[e2] = (_Float16)p1[e2];
      }
    }
    // W3 A-fragment: rows padded 5 -> 16; a[e2] = W3[m][8kg+e2] (zero for m>=5)
    half8 w3f;
    #pragma unroll
    for (int e2 = 0; e2 < 8; ++e2) {
      w3f[e2] = (m < 5) ? (_Float16)W3[m * 32 + 8 * kg + e2] : (_Float16)0.f;
    }

    // W1/b1 packed pairs: neurons (8kg+2p, 8kg+2p+1)
    __half2 w1z[4], w1l[4], w1n[4], b1p[4];
    #pragma unroll
    for (int p = 0; p < 4; ++p) {
      int n0 = 8 * kg + 2 * p;
      w1z[p] = __halves2half2(__float2half(W1[n0 * 3 + 0]), __float2half(W1[n0 * 3 + 3]));
      w1l[p] = __halves2half2(__float2half(W1[n0 * 3 + 1]), __float2half(W1[n0 * 3 + 4]));
      w1n[p] = __halves2half2(__float2half(W1[n0 * 3 + 2]), __float2half(W1[n0 * 3 + 5]));
      b1p[p] = __halves2half2(__float2half(b1[n0]), __float2half(b1[n0 + 1]));
    }
    float4v b2a = *(const float4v*)(b2 + 4 * kg);
    float4v b2b = *(const float4v*)(b2 + 16 + 4 * kg);
    const float b30 = b3[0], b31 = b3[1], b32 = b3[2], b33 = b3[3], b34 = b3[4];
    const float kS = 2.0609929f;     // log2(e)/0.7

    // shuffle sources for C-layout -> B-fragment redistribution
    const int srcA = (kg & 1) * 32 + m;
    const int srcB = srcA + 16;
    const bool hiHalf = (kg >= 2);

    #pragma unroll 1
    for (int pp = 0; pp < 16; ++pp) {
      const int ppx = pp ^ mx;
      __half2 z2 = __half2half2(gbuf[ch][0][m][ppx]);
      __half2 l2 = __half2half2(gbuf[ch][1][m][ppx]);
      __half2 n2 = __half2half2(gbuf[ch][2][m][ppx]);

      // layer 1 (packed pairs) + GELU -> f16 B-fragment
      union { __half2 h2[4]; half8 h8; } bu;
      #pragma unroll
      for (int p = 0; p < 4; ++p) {
        __half2 pre = __hfma2(w1z[p], z2, b1p[p]);
        pre = __hfma2(w1l[p], l2, pre);
        pre = __hfma2(w1n[p], n2, pre);
        bu.h2[p] = gelu_h2(pre);
      }

      // layer 2: single-pass f16 MFMA per g-tile
      float4v acc0 = {0.f,0.f,0.f,0.f}, acc1 = {0.f,0.f,0.f,0.f};
      acc0 = __builtin_amdgcn_mfma_f32_16x16x32_f16(w2f0, bu.h8, acc0, 0, 0, 0);
      acc1 = __builtin_amdgcn_mfma_f32_16x16x32_f16(w2f1, bu.h8, acc1, 0, 0, 0);

      // bias -> pack pairs -> packed GELU
      __half2 hh0 = __floats2half2_rn(acc0[0] + b2a[0], acc0[1] + b2a[1]);
      __half2 hh1 = __floats2half2_rn(acc0[2] + b2a[2], acc0[3] + b2a[3]);
      __half2 hh2 = __floats2half2_rn(acc1[0] + b2b[0], acc1[1] + b2b[1]);
      __half2 hh3 = __floats2half2_rn(acc1[2] + b2b[2], acc1[3] + b2b[3]);
      hh0 = gelu_h2(hh0); hh1 = gelu_h2(hh1); hh2 = gelu_h2(hh2); hh3 = gelu_h2(hh3);

      // redistribute C-layout h2 -> B-fragment rows 8kg+e2 (DEST-side hi/lo select)
      unsigned XA0 = __shfl(h2u(hh0), srcA);
      unsigned XA1 = __shfl(h2u(hh1), srcA);
      unsigned XA2 = __shfl(h2u(hh2), srcA);
      unsigned XA3 = __shfl(h2u(hh3), srcA);
      unsigned XB0 = __shfl(h2u(hh0), srcB);
      unsigned XB1 = __shfl(h2u(hh1), srcB);
      unsigned XB2 = __shfl(h2u(hh2), srcB);
      unsigned XB3 = __shfl(h2u(hh3), srcB);
      union { unsigned u[4]; half8 h8; } b2f;
      b2f.u[0] = hiHalf ? XA2 : XA0;
      b2f.u[1] = hiHalf ? XA3 : XA1;
      b2f.u[2] = hiHalf ? XB2 : XB0;
      b2f.u[3] = hiHalf ? XB3 : XB1;

      // layer 3: logits via MFMA (W3 padded 5->16 rows), f32 accum
      float4v d2 = {0.f,0.f,0.f,0.f};
      d2 = __builtin_amdgcn_mfma_f32_16x16x32_f16(w3f, b2f.h8, d2, 0, 0, 0);

      // broadcast the 5 logits of column m to all lanes
      float lg0 = __shfl(d2[0], m) + b30;
      float lg1 = __shfl(d2[1], m) + b31;
      float lg2 = __shfl(d2[2], m) + b32;
      float lg3 = __shfl(d2[3], m) + b33;
      float lg4 = __shfl(d2[0], m + 16) + b34;

      // softmax(logits/0.7), no max-sub (logits O(1) for this data)
      float e0 = fast_exp2(lg0 * kS);
      float e1 = fast_exp2(lg1 * kS);
      float e2 = fast_exp2(lg2 * kS);
      float e3 = fast_exp2(lg3 * kS);
      float e4 = fast_exp2(lg4 * kS);
      const float rs = fast_rcp(e0 + e1 + e2 + e3 + e4);

      float gw = e0;
      gw = (kg == 1) ? e1 : gw;
      gw = (kg == 2) ? e2 : gw;
      gw = (kg == 3) ? e3 : gw;
      gbuf[ch][kg][m][ppx] = __float2half(gw * rs);
      if (kg == 0) gbuf[ch][4][m][ppx] = __float2half(e4 * rs);
    }
  }
  // gates produced & consumed by the same wave -> no barrier needed

  // ======== Phase B: Toeplitz-MFMA conv (tap-hi only, bf16), chunk = wvi ======
  {
    const int hq = lane >> 4, p = lane & 15;

    const int Rs[5]    = {32, 64, 128, 256, 512};
    const int steps[5] = {3, 5, 9, 17, 33};
    const int cum[5]   = {0, 3, 8, 17, 34};

    float4v o0 = {0.f,0.f,0.f,0.f};

    #pragma unroll 1
    for (int s = 0; s < 5; ++s) {
      float4v a0 = {0.f,0.f,0.f,0.f};
      const int eb0 = PADL + 256 * wvi - Rs[s] + 16 * p + 8 * hq;
      const unsigned short* ahb = g_afrag_hi + (size_t)cum[s] * 512 + lane * 8;

      for (int st = 0; st < steps[s]; ++st) {
        short8 kh = *(const short8*)(ahb + st * 512);
        short8 b0h = *(const short8*)(&row_hi[eb0 + st * 32]);
        a0 = __builtin_amdgcn_mfma_f32_16x16x32_bf16(kh, b0h, a0, 0, 0, 0);
      }
      #pragma unroll
      for (int r = 0; r < 4; ++r) {
        const int row = 4 * hq + r;
        o0[r] = fmaf(__half2float(gbuf[wvi][s][row][p ^ (hq << 2)]), a0[r], o0[r]);
      }
    }

    if (WSPATH) {
      float* orow = outT + (size_t)(b * CC + c) * TT;
      *(float4v*)(orow + tbase + 256 * wvi + 16 * p + 4 * hq) = o0;
    } else {
      const size_t obase = (size_t)b * TT * CC + c;
      #pragma unroll
      for (int r = 0; r < 4; ++r) {
        out[obase + (size_t)(tbase + 256 * wvi + 16 * p + 4 * hq + r) * CC] = o0[r];
      }
    }
  }
}

extern "C" void kernel_launch(void* const* d_in, const int* in_sizes, int n_in,
                              void* d_out, int out_size, void* d_ws, size_t ws_size,
                              hipStream_t stream) {
  const float* x  = (const float*)d_in[0];
  const float* W1 = (const float*)d_in[1];
  const float* b1 = (const float*)d_in[2];
  const float* W2 = (const float*)d_in[3];
  const float* b2 = (const float*)d_in[4];
  const float* W3 = (const float*)d_in[5];
  const float* b3 = (const float*)d_in[6];
  float* outp = (float*)d_out;

  const size_t xt_bytes  = (size_t)BB * CC * TT * sizeof(unsigned short);  // 8.4 MB
  const size_t ot_bytes  = (size_t)BB * CC * TT * sizeof(float);           // 16.8 MB
  if (ws_size >= xt_bytes + ot_bytes) {
    unsigned short* xT = (unsigned short*)d_ws;
    float* outT = (float*)((char*)d_ws + xt_bytes);
    hipLaunchKernelGGL(transpose_in, dim3(BB * 32), dim3(256), 0, stream, x, xT);
    hipLaunchKernelGGL(fused_main_t<1>, dim3(BB * CC * 2), dim3(256), 0, stream,
                       x, xT, W1, b1, W2, b2, W3, b3, outT, outp);
    hipLaunchKernelGGL(transpose_out, dim3(BB * 32), dim3(256), 0, stream, outT, outp);
  } else {
    hipLaunchKernelGGL(init_frag, dim3(8), dim3(256), 0, stream);
    hipLaunchKernelGGL(fused_main_t<0>, dim3(BB * CC * 2), dim3(256), 0, stream,
                       x, (const unsigned short*)nullptr, W1, b1, W2, b2, W3, b3,
                       (float*)nullptr, outp);
  }
}

// Round 20
// 150.603 us; speedup vs baseline: 1.0627x; 1.0627x over previous
//
#include <hip/hip_runtime.h>
#include <hip/hip_fp16.h>
#include <math.h>

#define TT 2048
#define CC 64
#define BB 32
#define PAD 512
#define ROWL 3136          // padded bf16 row length

typedef __attribute__((ext_vector_type(8))) short short8;
typedef __attribute__((ext_vector_type(4))) float float4v;
typedef _Float16 half8 __attribute__((ext_vector_type(8)));

// Toeplitz A-fragment table: 67 K-steps x 64 lanes x 8 bf16 (hi only)
#define NSTEPS 67
__device__ unsigned short g_afrag_hi[NSTEPS * 64 * 8];

__device__ __forceinline__ float fast_rcp(float x) { return __builtin_amdgcn_rcpf(x); }
__device__ __forceinline__ float fast_exp2(float x) { return __builtin_amdgcn_exp2f(x); }
__device__ __forceinline__ float fast_log2(float x) { return __builtin_amdgcn_logf(x); }

__device__ __forceinline__ unsigned short f2bf(float x) {  // RNE bf16 round
  union { float f; unsigned u; } v; v.f = x;
  unsigned r = (v.u + 0x7FFFu + ((v.u >> 16) & 1u)) >> 16;
  return (unsigned short)r;
}
__device__ __forceinline__ unsigned h2u(__half2 h) { union { __half2 h; unsigned u; } c; c.h = h; return c.u; }

// packed-f16 GELU: x*sigma(1.595769x+0.0713548x^3); exp(-s)=exp2(x*(-2.3020231-0.10294217x^2))
__device__ __forceinline__ __half2 gelu_h2(__half2 x) {
  const __half2 c1 = __float2half2_rn(-0.10294217f);
  const __half2 c0 = __float2half2_rn(-2.3020231f);
  const __half2 one = __float2half2_rn(1.0f);
  __half2 u = __hmul2(x, x);
  __half2 w = __hmul2(x, __hfma2(c1, u, c0));
  __half2 e = h2exp2(w);
  return __hmul2(x, h2rcp(__hadd2(e, one)));
}

__device__ __forceinline__ void init_frag_body(int bid, int nb, int tid,
                                               float* ktap, double* ssum) {
  const int   Rr[5]  = {32, 64, 128, 256, 512};
  const float sg[5]  = {8.f, 16.f, 32.f, 64.f, 128.f};
  const int   off[5] = {0, 72, 208, 472, 984};

  for (int idx = tid; idx < 2016; idx += 256) {
    int s = (idx < 72) ? 0 : (idx < 208) ? 1 : (idx < 472) ? 2 : (idx < 984) ? 3 : 4;
    int d = idx - off[s];
    float v = 0.f;
    if (d <= 2 * Rr[s]) {
      float n = (float)(d - Rr[s]) / sg[s];
      v = __expf(-0.5f * n * n);
    }
    ktap[idx] = v;
  }
  __syncthreads();
  if (tid < 5) {
    double sum = 0.0;
    for (int d = 0; d <= 2 * Rr[tid]; ++d) sum += (double)ktap[off[tid] + d];
    ssum[tid] = 1.0 / (sum + 1e-12);
  }
  __syncthreads();
  for (int idx = tid; idx < 2016; idx += 256) {
    int s = (idx < 72) ? 0 : (idx < 208) ? 1 : (idx < 472) ? 2 : (idx < 984) ? 3 : 4;
    ktap[idx] *= (float)ssum[s];
  }
  __syncthreads();

  const int cum[5] = {0, 3, 8, 17, 34};
  for (int e = bid * 256 + tid; e < NSTEPS * 64; e += nb * 256) {
    int stg = e >> 6, lane = e & 63;
    int s = (stg < 3) ? 0 : (stg < 8) ? 1 : (stg < 17) ? 2 : (stg < 34) ? 3 : 4;
    int st = stg - cum[s];
    int i = lane & 15, h = lane >> 4;
    for (int e2 = 0; e2 < 8; ++e2) {
      int d = st * 32 + 8 * h + e2 - i;
      float v = (d >= 0 && d <= 2 * Rr[s]) ? ktap[off[s] + d] : 0.f;
      g_afrag_hi[e * 8 + e2] = f2bf(v);
    }
  }
}

__global__ void init_frag() {
  __shared__ float ktap[2016];
  __shared__ double ssum[5];
  init_frag_body(blockIdx.x, gridDim.x, threadIdx.x, ktap, ssum);
}

// ---- transpose x [B,T,C] fp32 -> xT [B,C,T] bf16; blocks 0..7 also init frags ----
__global__ void transpose_in(const float* __restrict__ x, unsigned short* __restrict__ xT) {
  __shared__ float tile[64][65];
  __shared__ float ktap[2016];
  __shared__ double ssum[5];
  const int tid = threadIdx.x;
  const int b = blockIdx.x >> 5;
  const int t0 = (blockIdx.x & 31) * 64;

  const float* src = x + ((size_t)b * TT + t0) * CC;
  #pragma unroll
  for (int k = 0; k < 16; ++k) {
    int idx = k * 256 + tid;
    int row = idx >> 6, col = idx & 63;
    tile[row][col] = src[(size_t)row * CC + col];
  }
  __syncthreads();
  unsigned short* dst = xT + (size_t)b * CC * TT + t0;
  #pragma unroll
  for (int k = 0; k < 16; ++k) {
    int idx = k * 256 + tid;
    int c = idx >> 6, tt = idx & 63;
    dst[(size_t)c * TT + tt] = f2bf(tile[tt][c]);
  }
  if (blockIdx.x < 8) init_frag_body(blockIdx.x, 8, tid, ktap, ssum);
}

// ---- transpose outT [B,C,T] fp32 -> out [B,T,C] fp32 ----
__global__ void transpose_out(const float* __restrict__ outT, float* __restrict__ out) {
  __shared__ float tile[64][65];
  const int tid = threadIdx.x;
  const int b = blockIdx.x >> 5;
  const int t0 = (blockIdx.x & 31) * 64;

  const float* src = outT + (size_t)b * CC * TT + t0;
  #pragma unroll
  for (int k = 0; k < 16; ++k) {
    int idx = k * 256 + tid;
    int cc2 = idx >> 6, tt = idx & 63;
    tile[cc2][tt] = src[(size_t)cc2 * TT + tt];
  }
  __syncthreads();
  float* dst = out + ((size_t)b * TT + t0) * CC;
  #pragma unroll
  for (int k = 0; k < 16; ++k) {
    int idx = k * 256 + tid;
    int tt = idx >> 6, cc2 = idx & 63;
    dst[(size_t)tt * CC + cc2] = tile[cc2][tt];
  }
}

template <int WSPATH>
__launch_bounds__(256, 6)
__global__ void fused_main_t(const float* __restrict__ x, const unsigned short* __restrict__ xT,
                             const float* __restrict__ W1, const float* __restrict__ b1,
                             const float* __restrict__ W2, const float* __restrict__ b2,
                             const float* __restrict__ W3, const float* __restrict__ b3,
                             float* __restrict__ outT, float* __restrict__ out) {
  __shared__ unsigned short row_hi[ROWL];
  __shared__ __half gbuf[8][5][16][16];   // gates; s=0..2 aliased as feats; XOR-swizzled cols

  const int tid = threadIdx.x;
  const int blk = blockIdx.x;
  const int c = blk & (CC - 1);
  const int b = blk >> 6;

  // ---- stage reflect-padded row as bf16 ----
  if (WSPATH) {
    const unsigned short* xtr = xT + (size_t)(b * CC + c) * TT;
    for (int i2 = tid; i2 < ROWL; i2 += 256) {
      int t = i2 - PAD;
      t = (t < 0) ? -t : t;
      t = (t >= TT) ? (2 * TT - 2 - t) : t;
      row_hi[i2] = xtr[t];
    }
  } else {
    const float* xrow = x + (size_t)b * TT * CC + c;
    for (int i2 = tid; i2 < ROWL; i2 += 256) {
      int t = i2 - PAD;
      t = (t < 0) ? -t : t;
      t = (t >= TT) ? (2 * TT - 2 - t) : t;
      row_hi[i2] = f2bf(xrow[(size_t)t * CC]);
    }
  }
  __syncthreads();

  const int t0 = tid * 8;
  const int lane = tid & 63;
  const int wvi = tid >> 6;

  // ======== Phase A1: sliding-window stats (bf16 x) -> feats ========
  {
    float w24[24];
    {
      const unsigned short* ph = &row_hi[PAD + t0 - 8];
      unsigned hw[12];
      *(uint4*)&hw[0] = *(const uint4*)ph;
      *(uint4*)&hw[4] = *(const uint4*)(ph + 8);
      *(uint4*)&hw[8] = *(const uint4*)(ph + 16);
      #pragma unroll
      for (int m2 = 0; m2 < 12; ++m2) {
        union { unsigned u; float f; } a, bb;
        a.u  = (hw[m2] & 0xFFFFu) << 16;
        bb.u = hw[m2] & 0xFFFF0000u;
        w24[2 * m2]     = a.f;
        w24[2 * m2 + 1] = bb.f;
      }
    }

    float sm = 0.f, sq = 0.f, scv = 0.f;
    #pragma unroll
    for (int j = 0; j < 16; ++j) {
      float v = w24[1 + j];
      sm += v;
      sq  = fmaf(v, v, sq);
      scv = fmaf(v, (float)j - 7.5f, scv);
    }

    #pragma unroll
    for (int i = 0; i < 8; ++i) {
      const float xv   = w24[i + 8];
      const float mean = sm * 0.0625f;
      const float ex2  = sq * 0.0625f;
      const float var  = fmaxf(ex2 - mean * mean, 0.f);
      const float slope = scv * (1.0f / 340.0f);
      const float stdv = sqrtf(var + 1e-6f);
      float z = (xv - mean) * fast_rcp(stdv);
      z = fminf(fmaxf(z, -10.f), 10.f);
      float lv = fast_log2(var + 1e-6f) * 0.069314718f;   // *ln2/10 = ln(.)/10
      float ns = slope * fast_rcp(stdv + 1e-6f);
      ns = fminf(fmaxf(ns, -10.f), 10.f);

      const int e = t0 + i;
      const int ch = e >> 8, rr = e & 15, pp = (e >> 4) & 15;
      const int ppx = pp ^ ((rr >> 2) << 2);
      gbuf[ch][0][rr][ppx] = __float2half(z);
      gbuf[ch][1][rr][ppx] = __float2half(lv);
      gbuf[ch][2][rr][ppx] = __float2half(ns);

      if (i < 7) {
        const float xo = w24[i + 1], xn = w24[i + 17];
        scv = fmaf(8.5f, xo, fmaf(7.5f, xn, scv - sm));
        sm += (xn - xo);
        sq = fmaf(xn, xn, sq);
        sq = fmaf(-xo, xo, sq);
      }
    }
  }

  // ======== Phase A2: MLP, all three layers on/around MFMA ========
  {
    const int kg = lane >> 4;        // quarter index q
    const int m  = lane & 15;        // element column
    const int ch0 = 2 * wvi, ch1 = 2 * wvi + 1;
    const int mx = (m >> 2) << 2;    // XOR swizzle term for row m

    // W2 A-fragments (single-pass f16)
    half8 w2f0, w2f1;
    {
      const float* p0 = W2 + (size_t)m * 32 + 8 * kg;
      const float* p1 = W2 + (size_t)(16 + m) * 32 + 8 * kg;
      #pragma unroll
      for (int e2 = 0; e2 < 8; ++e2) {
        w2f0[e2] = (_Float16)p0[e2];
        w2f1[e2] = (_Float16)p1[e2];
      }
    }
    // W3 A-fragment: rows padded 5 -> 16; a[e2] = W3[m][8kg+e2] (zero for m>=5)
    half8 w3f;
    #pragma unroll
    for (int e2 = 0; e2 < 8; ++e2) {
      w3f[e2] = (m < 5) ? (_Float16)W3[m * 32 + 8 * kg + e2] : (_Float16)0.f;
    }

    // W1/b1 packed pairs: neurons (8kg+2p, 8kg+2p+1)
    __half2 w1z[4], w1l[4], w1n[4], b1p[4];
    #pragma unroll
    for (int p = 0; p < 4; ++p) {
      int n0 = 8 * kg + 2 * p;
      w1z[p] = __halves2half2(__float2half(W1[n0 * 3 + 0]), __float2half(W1[n0 * 3 + 3]));
      w1l[p] = __halves2half2(__float2half(W1[n0 * 3 + 1]), __float2half(W1[n0 * 3 + 4]));
      w1n[p] = __halves2half2(__float2half(W1[n0 * 3 + 2]), __float2half(W1[n0 * 3 + 5]));
      b1p[p] = __halves2half2(__float2half(b1[n0]), __float2half(b1[n0 + 1]));
    }
    float4v b2a = *(const float4v*)(b2 + 4 * kg);
    float4v b2b = *(const float4v*)(b2 + 16 + 4 * kg);
    const float b30 = b3[0], b31 = b3[1], b32 = b3[2], b33 = b3[3], b34 = b3[4];
    const float kS = 2.0609929f;     // log2(e)/0.7

    // shuffle sources for C-layout -> B-fragment redistribution
    const int srcA = (kg & 1) * 32 + m;
    const int srcB = srcA + 16;
    const bool hiHalf = (kg >= 2);

    auto do_col = [&](int ch, int pp) {
      const int ppx = pp ^ mx;
      __half2 z2 = __half2half2(gbuf[ch][0][m][ppx]);
      __half2 l2 = __half2half2(gbuf[ch][1][m][ppx]);
      __half2 n2 = __half2half2(gbuf[ch][2][m][ppx]);

      // layer 1 (packed pairs) + GELU -> f16 B-fragment
      union { __half2 h2[4]; half8 h8; } bu;
      #pragma unroll
      for (int p = 0; p < 4; ++p) {
        __half2 pre = __hfma2(w1z[p], z2, b1p[p]);
        pre = __hfma2(w1l[p], l2, pre);
        pre = __hfma2(w1n[p], n2, pre);
        bu.h2[p] = gelu_h2(pre);
      }

      // layer 2: single-pass f16 MFMA per g-tile
      float4v acc0 = {0.f,0.f,0.f,0.f}, acc1 = {0.f,0.f,0.f,0.f};
      acc0 = __builtin_amdgcn_mfma_f32_16x16x32_f16(w2f0, bu.h8, acc0, 0, 0, 0);
      acc1 = __builtin_amdgcn_mfma_f32_16x16x32_f16(w2f1, bu.h8, acc1, 0, 0, 0);

      // bias -> pack pairs -> packed GELU
      __half2 hh0 = __floats2half2_rn(acc0[0] + b2a[0], acc0[1] + b2a[1]);
      __half2 hh1 = __floats2half2_rn(acc0[2] + b2a[2], acc0[3] + b2a[3]);
      __half2 hh2 = __floats2half2_rn(acc1[0] + b2b[0], acc1[1] + b2b[1]);
      __half2 hh3 = __floats2half2_rn(acc1[2] + b2b[2], acc1[3] + b2b[3]);
      hh0 = gelu_h2(hh0); hh1 = gelu_h2(hh1); hh2 = gelu_h2(hh2); hh3 = gelu_h2(hh3);

      // redistribute C-layout h2 -> B-fragment rows 8kg+e2 (DEST-side hi/lo select)
      unsigned XA0 = __shfl(h2u(hh0), srcA);
      unsigned XA1 = __shfl(h2u(hh1), srcA);
      unsigned XA2 = __shfl(h2u(hh2), srcA);
      unsigned XA3 = __shfl(h2u(hh3), srcA);
      unsigned XB0 = __shfl(h2u(hh0), srcB);
      unsigned XB1 = __shfl(h2u(hh1), srcB);
      unsigned XB2 = __shfl(h2u(hh2), srcB);
      unsigned XB3 = __shfl(h2u(hh3), srcB);
      union { unsigned u[4]; half8 h8; } b2f;
      b2f.u[0] = hiHalf ? XA2 : XA0;
      b2f.u[1] = hiHalf ? XA3 : XA1;
      b2f.u[2] = hiHalf ? XB2 : XB0;
      b2f.u[3] = hiHalf ? XB3 : XB1;

      // layer 3: logits via MFMA (W3 padded 5->16 rows), f32 accum
      float4v d2 = {0.f,0.f,0.f,0.f};
      d2 = __builtin_amdgcn_mfma_f32_16x16x32_f16(w3f, b2f.h8, d2, 0, 0, 0);

      // broadcast the 5 logits of column m to all lanes
      float lg0 = __shfl(d2[0], m) + b30;
      float lg1 = __shfl(d2[1], m) + b31;
      float lg2 = __shfl(d2[2], m) + b32;
      float lg3 = __shfl(d2[3], m) + b33;
      float lg4 = __shfl(d2[0], m + 16) + b34;

      // softmax(logits/0.7), no max-sub (logits O(1) for this data)
      float e0 = fast_exp2(lg0 * kS);
      float e1 = fast_exp2(lg1 * kS);
      float e2 = fast_exp2(lg2 * kS);
      float e3 = fast_exp2(lg3 * kS);
      float e4 = fast_exp2(lg4 * kS);
      const float rs = fast_rcp(e0 + e1 + e2 + e3 + e4);

      float gw = e0;
      gw = (kg == 1) ? e1 : gw;
      gw = (kg == 2) ? e2 : gw;
      gw = (kg == 3) ? e3 : gw;
      gbuf[ch][kg][m][ppx] = __float2half(gw * rs);
      if (kg == 0) gbuf[ch][4][m][ppx] = __float2half(e4 * rs);
    };

    #pragma unroll 1
    for (int pp = 0; pp < 16; ++pp) {
      do_col(ch0, pp);
      do_col(ch1, pp);
    }
  }
  // gates produced & consumed by the same wave -> no barrier needed

  // ======== Phase B: Toeplitz-MFMA conv (tap-hi only, bf16) ========
  {
    const int hq = lane >> 4, p = lane & 15;
    const int ch0 = 2 * wvi, ch1 = 2 * wvi + 1;

    const int Rs[5]    = {32, 64, 128, 256, 512};
    const int steps[5] = {3, 5, 9, 17, 33};
    const int cum[5]   = {0, 3, 8, 17, 34};

    float4v o0 = {0.f,0.f,0.f,0.f}, o1 = {0.f,0.f,0.f,0.f};

    #pragma unroll 1
    for (int s = 0; s < 5; ++s) {
      float4v a0 = {0.f,0.f,0.f,0.f}, a1 = {0.f,0.f,0.f,0.f};
      const int eb0 = PAD + 256 * ch0 - Rs[s] + 16 * p + 8 * hq;
      const int eb1 = eb0 + 256;
      const unsigned short* ahb = g_afrag_hi + (size_t)cum[s] * 512 + lane * 8;

      for (int st = 0; st < steps[s]; ++st) {
        short8 kh = *(const short8*)(ahb + st * 512);
        short8 b0h = *(const short8*)(&row_hi[eb0 + st * 32]);
        short8 b1h = *(const short8*)(&row_hi[eb1 + st * 32]);
        a0 = __builtin_amdgcn_mfma_f32_16x16x32_bf16(kh, b0h, a0, 0, 0, 0);
        a1 = __builtin_amdgcn_mfma_f32_16x16x32_bf16(kh, b1h, a1, 0, 0, 0);
      }
      #pragma unroll
      for (int r = 0; r < 4; ++r) {
        const int px = p ^ (hq << 2);   // row = 4hq+r -> swizzle term (hq<<2)
        o0[r] = fmaf(__half2float(gbuf[ch0][s][4 * hq + r][px]), a0[r], o0[r]);
        o1[r] = fmaf(__half2float(gbuf[ch1][s][4 * hq + r][px]), a1[r], o1[r]);
      }
    }

    if (WSPATH) {
      float* orow = outT + (size_t)(b * CC + c) * TT;
      *(float4v*)(orow + 256 * ch0 + 16 * p + 4 * hq) = o0;
      *(float4v*)(orow + 256 * ch1 + 16 * p + 4 * hq) = o1;
    } else {
      const size_t obase = (size_t)b * TT * CC + c;
      #pragma unroll
      for (int r = 0; r < 4; ++r) {
        out[obase + (size_t)(256 * ch0 + 16 * p + 4 * hq + r) * CC] = o0[r];
        out[obase + (size_t)(256 * ch1 + 16 * p + 4 * hq + r) * CC] = o1[r];
      }
    }
  }
}

extern "C" void kernel_launch(void* const* d_in, const int* in_sizes, int n_in,
                              void* d_out, int out_size, void* d_ws, size_t ws_size,
                              hipStream_t stream) {
  const float* x  = (const float*)d_in[0];
  const float* W1 = (const float*)d_in[1];
  const float* b1 = (const float*)d_in[2];
  const float* W2 = (const float*)d_in[3];
  const float* b2 = (const float*)d_in[4];
  const float* W3 = (const float*)d_in[5];
  const float* b3 = (const float*)d_in[6];
  float* outp = (float*)d_out;

  const size_t xt_bytes  = (size_t)BB * CC * TT * sizeof(unsigned short);  // 8.4 MB
  const size_t ot_bytes  = (size_t)BB * CC * TT * sizeof(float);           // 16.8 MB
  if (ws_size >= xt_bytes + ot_bytes) {
    unsigned short* xT = (unsigned short*)d_ws;
    float* outT = (float*)((char*)d_ws + xt_bytes);
    hipLaunchKernelGGL(transpose_in, dim3(BB * 32), dim3(256), 0, stream, x, xT);
    hipLaunchKernelGGL(fused_main_t<1>, dim3(BB * CC), dim3(256), 0, stream,
                       x, xT, W1, b1, W2, b2, W3, b3, outT, outp);
    hipLaunchKernelGGL(transpose_out, dim3(BB * 32), dim3(256), 0, stream, outT, outp);
  } else {
    hipLaunchKernelGGL(init_frag, dim3(8), dim3(256), 0, stream);
    hipLaunchKernelGGL(fused_main_t<0>, dim3(BB * CC), dim3(256), 0, stream,
                       x, (const unsigned short*)nullptr, W1, b1, W2, b2, W3, b3,
                       (float*)nullptr, outp);
  }
}